// Round 7
// baseline (185.919 us; speedup 1.0000x reference)
//
#include <hip/hip_runtime.h>

#define NIN    128
#define NOUT   512
#define NBATCH 16384
#define KF     8384            // native feature count
#define KP2    8832            // aligned-padded K order: 16 linear + 1088 cross groups, x8
#define NG     (KP2 / 8)       // 1104 groups
#define NTK2   (KP2 / 64)      // 138 K-tiles (even)
#define NPAIR  (NTK2 / 2)      // 69 pairs
#define XSP    136             // xS pitch (elems): 272 B, col 135 = ones
#define NTK    (KF / 64)       // 131 (fallback)
#define XP     136
#define AP     72

typedef float f32x4  __attribute__((ext_vector_type(4)));
typedef float f32x16 __attribute__((ext_vector_type(16)));
typedef __bf16 bf16x8 __attribute__((ext_vector_type(8)));
typedef __bf16 bf16x4 __attribute__((ext_vector_type(4)));
typedef unsigned int u32x4 __attribute__((ext_vector_type(4)));

__device__ __forceinline__ int triS(int i) { return (i * (257 - i)) >> 1; }

__device__ __forceinline__ void load_lds_16B(const void* g, void* l) {
  __builtin_amdgcn_global_load_lds(
      (const __attribute__((address_space(1))) void*)g,
      (__attribute__((address_space(3))) void*)l, 16, 0, 0);
}

// ================= K-order table (round-3 verified) =================
__global__ void k_tbl(unsigned int* __restrict__ tbl)
{
  int g = blockIdx.x * 256 + threadIdx.x;
  if (g >= NG) return;
  unsigned int e;
  if (g < 16) {
    e = 135u | ((unsigned)(g * 8) << 16);
  } else {
    int gp = g - 16;
    int b = 0;
    #pragma unroll
    for (int bb = 1; bb <= 15; ++bb) {
      int C = 8 * (16 * bb - bb * (bb - 1) / 2);
      if (gp >= C) b = bb;
    }
    int C   = 8 * (16 * b - b * (b - 1) / 2);
    int r   = gp - C;
    int per = 16 - b;
    int i   = 8 * b + r / per;
    int q   = r % per;
    e = (unsigned)i | ((unsigned)(8 * b + 8 * q) << 16);
  }
  tbl[g] = e;
}

// ================= Wt2[n][k'] = bf16(W[src(k')][n]); pads -> 0 (verified) =====
__global__ void k_wt2(const float* __restrict__ W,
                      const unsigned int* __restrict__ tbl,
                      __bf16* __restrict__ Wt)
{
  __shared__ __bf16 tile[64][65];
  const int kb   = blockIdx.x >> 3;
  const int nbw  = blockIdx.x & 7;
  const int lane = threadIdx.x & 63;
  const int grp  = threadIdx.x >> 6;
  #pragma unroll 4
  for (int it = 0; it < 16; ++it) {
    int kl = it * 4 + grp;
    int kp = kb * 64 + kl;
    unsigned int e = tbl[kp >> 3];
    int i = (int)(e & 0xFFFFu);
    int j = (int)(e >> 16) + (kp & 7);
    float v = 0.f;
    if (i == 135) {
      v = W[(size_t)kp * NOUT + nbw * 64 + lane];
    } else if (j >= i) {
      int src = 128 + i * 128 - i * (i - 1) / 2 + (j - i);
      v = W[(size_t)src * NOUT + nbw * 64 + lane];
    }
    tile[kl][lane] = (__bf16)v;
  }
  __syncthreads();
  #pragma unroll 4
  for (int it = 0; it < 16; ++it) {
    int nl = it * 4 + grp;
    Wt[(size_t)(nbw * 64 + nl) * KP2 + kb * 64 + lane] = tile[lane][nl];
  }
}

// ---- epilogue helpers: template-static acc indexing (rule #20) ----
template<int NJ0>
__device__ __forceinline__ void dump2(const f32x16 (&acc)[2][4], float* myreg, int lane)
{
  #pragma unroll
  for (int mi = 0; mi < 2; ++mi)
    #pragma unroll
    for (int fj = 0; fj < 2; ++fj)
      #pragma unroll
      for (int rr = 0; rr < 4; ++rr) {
        f32x4 v;
        #pragma unroll
        for (int q = 0; q < 4; ++q) v[q] = acc[mi][NJ0 + fj][rr * 4 + q];
        *reinterpret_cast<f32x4*>(myreg + ((mi * 2 + fj) * 4 + rr) * 256 + lane * 4) = v;
      }
}

template<int NJ0>
__device__ __forceinline__ void out2(const f32x16 (&acc)[2][4], const float* preg,
                                     const float* bias, float* out, int lane,
                                     int nbase, int mbase)
{
  #pragma unroll
  for (int fj = 0; fj < 2; ++fj) {
    int n = nbase + (NJ0 + fj) * 32 + (lane & 31);
    float bv = bias[n];
    #pragma unroll
    for (int mi = 0; mi < 2; ++mi)
      #pragma unroll
      for (int rr = 0; rr < 4; ++rr) {
        f32x4 o = *reinterpret_cast<const f32x4*>(
            preg + ((mi * 2 + fj) * 4 + rr) * 256 + lane * 4);
        #pragma unroll
        for (int q = 0; q < 4; ++q) {
          int row = mbase + mi * 32 + q + 8 * rr + 4 * (lane >> 5);
          out[(size_t)row * NOUT + n] = acc[mi][NJ0 + fj][rr * 4 + q] + o[q] + bv;
        }
      }
  }
}

// ========== main GEMM: 128m x 128n block, 4 waves (wm, wk k-parity) ==========
// 32x32x16 MFMA, wave = 64m x 128n on k-tiles kt===wk (mod 2).
// Bt staged by global_load_lds (linear dest + per-lane swizzled source, m173);
// gll(p+1) issued after read-done barrier, latency covered by A-gen VALU.
__global__ __launch_bounds__(256, 2) void k_gemm5(
    const float* __restrict__ X,
    const __bf16* __restrict__ Wt,
    const float* __restrict__ bias,
    const unsigned int* __restrict__ tbl,
    float* __restrict__ out)
{
  __shared__ __align__(16) __bf16 xS[128 * XSP];   // 34816 B, col135 = 1.0
  __shared__ __align__(16) __bf16 Bt[2 * 128 * 64];// 32768 B, slot s = chunk^(n&7)
  __shared__ unsigned short tbl_s[NG];             // 2208 B  (total 69792 B)

  const int tid  = threadIdx.x;
  const int lane = tid & 63;
  const int wid  = tid >> 6;
  const int wm   = wid & 1;           // m-half
  const int wk   = wid >> 1;          // k-parity
  const int mb   = blockIdx.x >> 2;
  const int nb   = blockIdx.x & 3;    // each XCD sees one 2.26MB Wt slice

  for (int g = tid; g < NG; g += 256) {
    unsigned int e = tbl[g];
    tbl_s[g] = (unsigned short)((e & 0xFFu) | ((e >> 16) << 8));  // i | j0<<8
  }

  { // stage xS (row-major bf16) + ones column
    const float* xg = X + (size_t)mb * 128 * NIN;
    const int m = tid >> 1, h = tid & 1;
    #pragma unroll
    for (int it = 0; it < 16; ++it) {
      int c4 = h * 64 + it * 4;
      f32x4 v = *reinterpret_cast<const f32x4*>(xg + m * NIN + c4);
      bf16x4 b;
      #pragma unroll
      for (int e2 = 0; e2 < 4; ++e2) b[e2] = (__bf16)v[e2];
      *reinterpret_cast<bf16x4*>(&xS[m * XSP + c4]) = b;
    }
    if (tid < 128) xS[tid * XSP + 135] = (__bf16)1.0f;
  }
  __syncthreads();   // xS + tbl_s visible

  // gll staging: 32 chunks of 1KB per pair; wave wid covers chunks wid*8..+7.
  // lane writes 16B at dest slot (lane&7), sourcing W chunk (lane&7)^(lane>>3)
  // -> LDS image Bt[n][s] = W[n][s ^ (n&7)]  (read with s = cb ^ (n&7)).
  auto stage_pair = [&](int p) {
    #pragma unroll
    for (int ig = 0; ig < 8; ++ig) {
      int cg = wid * 8 + ig;
      int t  = cg >> 4;        // tile parity within pair
      int ct = cg & 15;        // 8-row group
      const __bf16* src = Wt
          + (size_t)(nb * 128 + ct * 8 + (lane >> 3)) * KP2
          + (size_t)(2 * p + t) * 64
          + (((lane & 7) ^ (lane >> 3)) * 8);
      load_lds_16B(src, &Bt[t * 8192 + ct * 512]);
    }
  };

  f32x16 acc[2][4];
  #pragma unroll
  for (int a = 0; a < 2; ++a)
    #pragma unroll
    for (int b = 0; b < 4; ++b)
      acc[a][b] = (f32x16)(0.f);

  stage_pair(0);

  for (int p = 0; p < NPAIR; ++p) {
    const int kt = 2 * p + wk;

    // ---- A-gen into registers (covers gll latency; touches only xS) ----
    bf16x8 af[2][4];
    #pragma unroll
    for (int ks = 0; ks < 4; ++ks) {
      unsigned short e = tbl_s[kt * 8 + ks * 2 + (lane >> 5)];
      const int i  = (int)(e & 0xFFu);
      const int j0 = (int)(e >> 8);
      #pragma unroll
      for (int mi = 0; mi < 2; ++mi) {
        int m = wm * 64 + mi * 32 + (lane & 31);
        u32x4 va = *reinterpret_cast<const u32x4*>(&xS[m * XSP + j0]);
        unsigned short svu = *reinterpret_cast<const unsigned short*>(&xS[m * XSP + i]);
        float sv = __builtin_bit_cast(float, (unsigned int)svu << 16);
        bf16x8 a;
        #pragma unroll
        for (int q = 0; q < 4; ++q) {
          float lo = __builtin_bit_cast(float, va[q] << 16);
          float hi = __builtin_bit_cast(float, va[q] & 0xFFFF0000u);
          a[2 * q]     = (__bf16)(lo * sv);   // adjacent casts -> v_cvt_pk_bf16_f32
          a[2 * q + 1] = (__bf16)(hi * sv);
        }
        af[mi][ks] = a;
      }
    }

    __syncthreads();   // gll(pair p) drained (own vmcnt) + visible to all waves

    // ---- MFMA phase: 32x32x16, B-frags read from swizzled Bt ----
    __builtin_amdgcn_s_setprio(1);
    #pragma unroll
    for (int ks = 0; ks < 4; ++ks) {
      const int cb = ks * 2 + (lane >> 5);          // k-chunk index (16B units)
      #pragma unroll
      for (int ni = 0; ni < 4; ++ni) {
        int n = ni * 32 + (lane & 31);
        bf16x8 bv = *reinterpret_cast<const bf16x8*>(
            &Bt[wk * 8192 + n * 64 + ((cb ^ (n & 7)) * 8)]);
        #pragma unroll
        for (int mi = 0; mi < 2; ++mi)
          acc[mi][ni] = __builtin_amdgcn_mfma_f32_32x32x16_bf16(
              af[mi][ks], bv, acc[mi][ni], 0, 0, 0);
      }
    }
    __builtin_amdgcn_s_setprio(0);

    __syncthreads();   // all waves done reading pair p
    if (p + 1 < NPAIR) stage_pair(p + 1);
  }

  // ---- epilogue: k-parity partial exchange via freed LDS (Bt 32K + xS 32K) ----
  {
    float* reg0 = reinterpret_cast<float*>(&Bt[0]);
    float* reg1 = reinterpret_cast<float*>(&xS[0]);
    float* myreg = (wid < 2 ? reg0 : reg1) + (wid & 1) * 4096;   // 16 KB region
    if (wk == 0) dump2<2>(acc, myreg, lane);   // dump the half I don't output
    else         dump2<0>(acc, myreg, lane);
    __syncthreads();
    const int pw = wid ^ 2;                    // partner: same wm, other wk
    const float* preg = (pw < 2 ? reg0 : reg1) + (pw & 1) * 4096;
    const int nbase = nb * 128;
    const int mbase = mb * 128 + wm * 64;
    if (wk == 0) out2<0>(acc, preg, bias, out, lane, nbase, mbase);
    else         out2<2>(acc, preg, bias, out, lane, nbase, mbase);
  }
}

// ================= fallback tiers (round-2/3 verified) =================
__global__ void k_wt(const float* __restrict__ W, __bf16* __restrict__ Wt)
{
  __shared__ __bf16 tile[64][65];
  const int kb   = blockIdx.x >> 3;
  const int nbw  = blockIdx.x & 7;
  const int lane = threadIdx.x & 63;
  const int grp  = threadIdx.x >> 6;
  #pragma unroll 4
  for (int it = 0; it < 16; ++it) {
    int kl = it * 4 + grp;
    tile[kl][lane] = (__bf16)W[(size_t)(kb * 64 + kl) * NOUT + nbw * 64 + lane];
  }
  __syncthreads();
  #pragma unroll 4
  for (int it = 0; it < 16; ++it) {
    int nl = it * 4 + grp;
    Wt[(size_t)(nbw * 64 + nl) * KF + kb * 64 + lane] = tile[lane][nl];
  }
}

template<bool WS>
__global__ __launch_bounds__(256, 2) void k_gemm(
    const float* __restrict__ X, const float* __restrict__ W,
    const __bf16* __restrict__ Wt, const float* __restrict__ bias,
    float* __restrict__ out)
{
  __shared__ __align__(16) __bf16 xT[128 * XP];
  __shared__ __align__(16) __bf16 At[128 * AP];
  __shared__ __align__(16) __bf16 Bt[128 * AP];
  const int tid = threadIdx.x, lane = tid & 63, wid = tid >> 6;
  const int mb = blockIdx.x >> 2, nb = blockIdx.x & 3;
  const int wr = wid >> 1, wc = wid & 1, kk = lane;
  {
    const float* xg = X + (size_t)mb * 128 * 128;
    #pragma unroll
    for (int it = 0; it < 16; ++it) {
      int row = it * 8 + (tid >> 5);
      int c4 = (tid & 31) * 4;
      f32x4 v = *reinterpret_cast<const f32x4*>(xg + row * 128 + c4);
      #pragma unroll
      for (int e = 0; e < 4; ++e) xT[(c4 + e) * XP + row] = (__bf16)v[e];
    }
  }
  f32x4 acc[4][4];
  #pragma unroll
  for (int a = 0; a < 4; ++a)
    #pragma unroll
    for (int b = 0; b < 4; ++b) acc[a][b] = f32x4{0.f, 0.f, 0.f, 0.f};
  __syncthreads();
  for (int kt = 0; kt < NTK; ++kt) {
    if (WS) {
      #pragma unroll
      for (int rep = 0; rep < 4; ++rep) {
        int id = rep * 256 + tid;
        int n = id >> 3, c = id & 7;
        bf16x8 v = *reinterpret_cast<const bf16x8*>(Wt + (size_t)(nb * 128 + n) * KF + kt * 64 + c * 8);
        *reinterpret_cast<bf16x8*>(&Bt[n * AP + c * 8]) = v;
      }
    } else {
      #pragma unroll
      for (int rep = 0; rep < 8; ++rep) {
        int r = rep * 8 + (tid >> 5);
        int cL = (tid & 31) * 4;
        f32x4 wv = *reinterpret_cast<const f32x4*>(W + (size_t)(kt * 64 + r) * NOUT + nb * 128 + cL);
        #pragma unroll
        for (int e = 0; e < 4; ++e) Bt[(cL + e) * AP + r] = (__bf16)wv[e];
      }
    }
    const int k = kt * 64 + kk;
    if (kt >= 2) {
      int idx = k - 128;
      int i = (int)((257.0f - sqrtf((float)(66049 - 8 * idx))) * 0.5f);
      if (i < 0) i = 0;
      if (i > 127) i = 127;
      while (i < 127 && triS(i + 1) <= idx) ++i;
      while (i > 0 && triS(i) > idx) --i;
      int j = i + (idx - triS(i));
      #pragma unroll
      for (int mg = 0; mg < 4; ++mg) {
        int m0 = wid * 32 + mg * 8;
        bf16x8 va = *reinterpret_cast<const bf16x8*>(&xT[i * XP + m0]);
        bf16x8 vb = *reinterpret_cast<const bf16x8*>(&xT[j * XP + m0]);
        #pragma unroll
        for (int q = 0; q < 8; ++q)
          At[(m0 + q) * AP + kk] = (__bf16)((float)va[q] * (float)vb[q]);
      }
    } else {
      #pragma unroll
      for (int mg = 0; mg < 4; ++mg) {
        int m0 = wid * 32 + mg * 8;
        bf16x8 va = *reinterpret_cast<const bf16x8*>(&xT[k * XP + m0]);
        #pragma unroll
        for (int q = 0; q < 8; ++q) At[(m0 + q) * AP + kk] = va[q];
      }
    }
    __syncthreads();
    #pragma unroll
    for (int kh = 0; kh < 2; ++kh) {
      const int koff = kh * 32 + 8 * (lane >> 4);
      bf16x8 af2[4], bfv[4];
      #pragma unroll
      for (int mi = 0; mi < 4; ++mi) {
        int m = wr * 64 + mi * 16 + (lane & 15);
        af2[mi] = *reinterpret_cast<const bf16x8*>(&At[m * AP + koff]);
      }
      #pragma unroll
      for (int ni = 0; ni < 4; ++ni) {
        int n = wc * 64 + ni * 16 + (lane & 15);
        bfv[ni] = *reinterpret_cast<const bf16x8*>(&Bt[n * AP + koff]);
      }
      #pragma unroll
      for (int mi = 0; mi < 4; ++mi)
        #pragma unroll
        for (int ni = 0; ni < 4; ++ni)
          acc[mi][ni] = __builtin_amdgcn_mfma_f32_16x16x32_bf16(af2[mi], bfv[ni], acc[mi][ni], 0, 0, 0);
    }
    __syncthreads();
  }
  #pragma unroll
  for (int ni = 0; ni < 4; ++ni) {
    int n = nb * 128 + wc * 64 + ni * 16 + (lane & 15);
    float bv = bias[n];
    #pragma unroll
    for (int mi = 0; mi < 4; ++mi) {
      int mloc = wr * 64 + mi * 16 + ((lane >> 4) << 2);
      #pragma unroll
      for (int q = 0; q < 4; ++q) {
        size_t row = (size_t)mb * 128 + mloc + q;
        out[row * NOUT + n] = acc[mi][ni][q] + bv;
      }
    }
  }
}

extern "C" void kernel_launch(void* const* d_in, const int* in_sizes, int n_in,
                              void* d_out, int out_size, void* d_ws, size_t ws_size,
                              hipStream_t stream)
{
  const float* X    = (const float*)d_in[0];
  const float* W    = (const float*)d_in[1];
  const float* bias = (const float*)d_in[2];
  float* out        = (float*)d_out;

  const size_t wt2_bytes = (size_t)NOUT * KP2 * 2;            // 9,043,968
  const size_t need2     = wt2_bytes + (size_t)NG * 4;
  const size_t wt_bytes  = (size_t)NOUT * KF * 2;

  if (d_ws && ws_size >= need2) {
    __bf16* Wt        = (__bf16*)d_ws;
    unsigned int* tbl = (unsigned int*)((char*)d_ws + wt2_bytes);
    k_tbl<<<dim3((NG + 255) / 256), dim3(256), 0, stream>>>(tbl);
    k_wt2<<<dim3(NTK2 * 8), dim3(256), 0, stream>>>(W, tbl, Wt);
    k_gemm5<<<dim3((NBATCH / 128) * 4), dim3(256), 0, stream>>>(X, Wt, bias, tbl, out);
  } else if (d_ws && ws_size >= wt_bytes) {
    __bf16* Wt = (__bf16*)d_ws;
    k_wt<<<dim3(NTK * 8), dim3(256), 0, stream>>>(W, Wt);
    k_gemm<true><<<dim3((NBATCH / 128) * 4), dim3(256), 0, stream>>>(X, W, Wt, bias, out);
  } else {
    k_gemm<false><<<dim3((NBATCH / 128) * 4), dim3(256), 0, stream>>>(X, W, nullptr, bias, out);
  }
}